// Round 3
// baseline (202.084 us; speedup 1.0000x reference)
//
#include <hip/hip_runtime.h>
#include <hip/hip_cooperative_groups.h>

namespace cg = cooperative_groups;

// Problem: B=4, Q=256, K=256, H=768, D=768, NUM_LEN=100
// s = q + k + emb[lm]  (never materialized; all linear maps distribute)
// ws float layout: qP[1024][8] @0, kP[1024][8] @8192, eP[100][8] @16384,
//                  probs[1024][256] @17408
#define Hn 768
#define Bn 4
#define Qn 256
#define Kn 256
#define Dn 768
#define WS_KP 8192
#define WS_EP 16384
#define WS_PROBS 17408

__device__ __forceinline__ void fma4(float4& a, float s, const float4& v) {
    a.x = fmaf(s, v.x, a.x); a.y = fmaf(s, v.y, a.y);
    a.z = fmaf(s, v.z, a.z); a.w = fmaf(s, v.w, a.w);
}

// ---------------- mega kernel: proj -> score -> pv with grid syncs ----------
__global__ __launch_bounds__(256, 3) void mega_kernel(
    const float* __restrict__ q, const float* __restrict__ k,
    const float* __restrict__ m, const float* __restrict__ am,
    const float* __restrict__ emb, const float* __restrict__ W1,
    const float* __restrict__ b1, const float* __restrict__ W2,
    const float* __restrict__ b2, const int* __restrict__ lm,
    float* __restrict__ scores_out, float* __restrict__ content_out,
    float* __restrict__ ws)
{
    cg::grid_group grid = cg::this_grid();
    __shared__ float lds[10240];            // 40 KB, reused across phases
    float* probs = ws + WS_PROBS;
    int t = threadIdx.x;
    int wave = t >> 6, lane = t & 63;

    // ---------------- phase 1: projections (wave per row) ----------------
    {
        int wid = blockIdx.x * 4 + wave;    // 0..3071, rows 0..2147
        if (wid < 2148) {
            const float* src; float* dst;
            if (wid < 1024)      { src = q + wid * Hn;          dst = ws + wid * 8; }
            else if (wid < 2048) { src = k + (wid - 1024) * Hn; dst = ws + WS_KP + (wid - 1024) * 8; }
            else                 { src = emb + (wid - 2048) * Hn; dst = ws + WS_EP + (wid - 2048) * 8; }
            float acc[6] = {0.f, 0.f, 0.f, 0.f, 0.f, 0.f};
            #pragma unroll
            for (int i = 0; i < 3; ++i) {
                int h = i * 256 + lane * 4;
                float4 x  = *(const float4*)&src[h];
                float4 w1 = *(const float4*)&W1[h];
                acc[0] += x.x * w1.x + x.y * w1.y + x.z * w1.z + x.w * w1.w;
                #pragma unroll
                for (int c = 0; c < 5; ++c) {
                    float4 w2 = *(const float4*)&W2[c * Hn + h];
                    acc[1 + c] += x.x * w2.x + x.y * w2.y + x.z * w2.z + x.w * w2.w;
                }
            }
            #pragma unroll
            for (int j = 0; j < 6; ++j) {
                float v = acc[j];
                #pragma unroll
                for (int off = 32; off > 0; off >>= 1)
                    v += __shfl_xor(v, off, 64);
                if (lane == 0) dst[j] = v;
            }
        }
    }
    grid.sync();

    // ---------------- phase 2: scores + probs (block per (b,q) row) -------
    {
        float* sc    = lds;          // 1280 floats
        float* wmaxA = lds + 1280;   // 4
        float* wsumA = lds + 1284;   // 4
        const float* qP = ws;
        const float* kP = ws + WS_KP;
        const float* eP = ws + WS_EP;
        for (int bq = blockIdx.x; bq < 1024; bq += 768) {
            int b = bq >> 8;
            float qp[6];
            #pragma unroll
            for (int j = 0; j < 6; ++j) qp[j] = qP[bq * 8 + j];

            int krow = b * Kn + t;
            float4 ka = *(const float4*)&kP[krow * 8];
            float4 kb = *(const float4*)&kP[krow * 8 + 4];
            float kp[6] = {ka.x, ka.y, ka.z, ka.w, kb.x, kb.y};

            int l = lm[(size_t)bq * Kn + t];
            float4 ea = *(const float4*)&eP[l * 8];
            float4 eb = *(const float4*)&eP[l * 8 + 4];
            float ep[6] = {ea.x, ea.y, ea.z, ea.w, eb.x, eb.y};

            float amv = am[(size_t)bq * Kn + t];
            float as  = (qp[0] + kp[0] + ep[0] + b1[0]) * amv;

            float lg[5];
            float mx5 = -1e30f;
            #pragma unroll
            for (int c = 0; c < 5; ++c) {
                lg[c] = qp[c + 1] + kp[c + 1] + ep[c + 1] + b2[c];
                mx5 = fmaxf(mx5, lg[c]);
            }
            float s5 = 0.f;
            #pragma unroll
            for (int c = 0; c < 5; ++c) { lg[c] = __expf(lg[c] - mx5); s5 += lg[c]; }
            float inv5 = 1.f / s5;
            #pragma unroll
            for (int c = 0; c < 5; ++c) sc[t * 5 + c] = lg[c] * inv5;

            float wm = as;
            #pragma unroll
            for (int off = 32; off > 0; off >>= 1) wm = fmaxf(wm, __shfl_xor(wm, off, 64));
            if (lane == 0) wmaxA[wave] = wm;
            __syncthreads();
            float mx = fmaxf(fmaxf(wmaxA[0], wmaxA[1]), fmaxf(wmaxA[2], wmaxA[3]));
            float e = __expf(as - mx);
            float wsum = e;
            #pragma unroll
            for (int off = 32; off > 0; off >>= 1) wsum += __shfl_xor(wsum, off, 64);
            if (lane == 0) wsumA[wave] = wsum;
            __syncthreads();
            float inv = 1.f / (wsumA[0] + wsumA[1] + wsumA[2] + wsumA[3]);
            probs[(size_t)bq * Kn + t] = e * inv;

            float4* so4 = (float4*)(scores_out + (size_t)bq * Kn * 5);
            const float4* sc4 = (const float4*)sc;
            so4[t] = sc4[t];
            if (t < 64) so4[256 + t] = sc4[256 + t];
            __syncthreads();   // protect sc before next row's writes
        }
    }
    grid.sync();

    // ---------------- phase 3: content = probs @ m -----------------------
    // block = (b:4, qt:32 [8 q rows], dt:6 [128 d]); thread: kh=t>>5 (8 k-
    // groups of 32), c4=t&31 (float4 col). p in LDS, 8-way k partials in LDS.
    {
        float*  p     = lds;                    // [8][256] = 2048 floats
        float4* parts = (float4*)(lds + 2048);  // [8 kh][8 qi][32 c4] = 2048 f4
        int bid = blockIdx.x;
        int dt = bid % 6;
        int qt = (bid / 6) & 31;
        int b  = bid / 192;
        int kh = t >> 5;
        int c4 = t & 31;

        const float4* psrc4 = (const float4*)(probs + (size_t)(b * Qn + qt * 8) * Kn);
        float4* p4 = (float4*)p;
        p4[t]       = psrc4[t];
        p4[t + 256] = psrc4[t + 256];
        __syncthreads();

        float4 acc[8];
        #pragma unroll
        for (int qi = 0; qi < 8; ++qi) acc[qi] = make_float4(0.f, 0.f, 0.f, 0.f);

        #pragma unroll
        for (int g = 0; g < 8; ++g) {
            int k0 = (kh << 5) + (g << 2);
            const float* mb = m + (size_t)(b * Kn + k0) * Dn + dt * 128 + (c4 << 2);
            float4 m0 = *(const float4*)(mb);
            float4 m1 = *(const float4*)(mb + Dn);
            float4 m2 = *(const float4*)(mb + 2 * Dn);
            float4 m3 = *(const float4*)(mb + 3 * Dn);
            #pragma unroll
            for (int qi = 0; qi < 8; ++qi) {
                float4 pv = *(const float4*)&p[qi * 256 + k0];
                fma4(acc[qi], pv.x, m0);
                fma4(acc[qi], pv.y, m1);
                fma4(acc[qi], pv.z, m2);
                fma4(acc[qi], pv.w, m3);
            }
        }
        #pragma unroll
        for (int qi = 0; qi < 8; ++qi) parts[(kh * 8 + qi) * 32 + c4] = acc[qi];
        __syncthreads();

        int qi2 = t >> 5, c42 = t & 31;
        float4 s = parts[qi2 * 32 + c42];
        #pragma unroll
        for (int kk = 1; kk < 8; ++kk) {
            float4 v = parts[(kk * 8 + qi2) * 32 + c42];
            s.x += v.x; s.y += v.y; s.z += v.z; s.w += v.w;
        }
        *(float4*)(content_out + (size_t)(b * Qn + qt * 8 + qi2) * Dn + dt * 128 + (c42 << 2)) = s;
    }
}

// ---------------- fallback kernels (R2 versions, proven) --------------------
__global__ __launch_bounds__(256) void proj_kernel(
    const float* __restrict__ q, const float* __restrict__ k,
    const float* __restrict__ emb, const float* __restrict__ W1,
    const float* __restrict__ W2, float* __restrict__ ws)
{
    int wid  = blockIdx.x * 4 + (threadIdx.x >> 6);
    int lane = threadIdx.x & 63;
    const float* src;
    float* dst;
    if (wid < 1024)      { src = q + wid * Hn;            dst = ws + wid * 8; }
    else if (wid < 2048) { src = k + (wid - 1024) * Hn;   dst = ws + WS_KP + (wid - 1024) * 8; }
    else {
        int r = wid - 2048;
        if (r >= 100) return;
        src = emb + r * Hn; dst = ws + WS_EP + r * 8;
    }
    float acc[6] = {0.f, 0.f, 0.f, 0.f, 0.f, 0.f};
    #pragma unroll
    for (int i = 0; i < 3; ++i) {
        int h = i * 256 + lane * 4;
        float4 x  = *(const float4*)&src[h];
        float4 w1 = *(const float4*)&W1[h];
        acc[0] += x.x * w1.x + x.y * w1.y + x.z * w1.z + x.w * w1.w;
        #pragma unroll
        for (int c = 0; c < 5; ++c) {
            float4 w2 = *(const float4*)&W2[c * Hn + h];
            acc[1 + c] += x.x * w2.x + x.y * w2.y + x.z * w2.z + x.w * w2.w;
        }
    }
    #pragma unroll
    for (int j = 0; j < 6; ++j) {
        float v = acc[j];
        #pragma unroll
        for (int off = 32; off > 0; off >>= 1)
            v += __shfl_xor(v, off, 64);
        if (lane == 0) dst[j] = v;
    }
}

__global__ __launch_bounds__(256) void score_kernel(
    const float* __restrict__ ws_proj, const float* __restrict__ am,
    const int* __restrict__ lm, const float* __restrict__ b1,
    const float* __restrict__ b2, float* __restrict__ scores_out,
    float* __restrict__ probs_out)
{
    const float* qP = ws_proj;
    const float* kP = ws_proj + WS_KP;
    const float* eP = ws_proj + WS_EP;
    int bq = blockIdx.x;
    int b  = bq >> 8;
    int t  = threadIdx.x;
    int wave = t >> 6, lane = t & 63;

    float qp[6];
    #pragma unroll
    for (int j = 0; j < 6; ++j) qp[j] = qP[bq * 8 + j];

    int krow = b * Kn + t;
    float4 ka = *(const float4*)&kP[krow * 8];
    float4 kb = *(const float4*)&kP[krow * 8 + 4];
    float kp[6] = {ka.x, ka.y, ka.z, ka.w, kb.x, kb.y};

    int l = lm[(size_t)bq * Kn + t];
    float4 ea = *(const float4*)&eP[l * 8];
    float4 eb = *(const float4*)&eP[l * 8 + 4];
    float ep[6] = {ea.x, ea.y, ea.z, ea.w, eb.x, eb.y};

    float amv = am[(size_t)bq * Kn + t];
    float as  = (qp[0] + kp[0] + ep[0] + b1[0]) * amv;

    __shared__ float sc[Kn * 5];
    float lg[5];
    float mx5 = -1e30f;
    #pragma unroll
    for (int c = 0; c < 5; ++c) {
        lg[c] = qp[c + 1] + kp[c + 1] + ep[c + 1] + b2[c];
        mx5 = fmaxf(mx5, lg[c]);
    }
    float s5 = 0.f;
    #pragma unroll
    for (int c = 0; c < 5; ++c) { lg[c] = __expf(lg[c] - mx5); s5 += lg[c]; }
    float inv5 = 1.f / s5;
    #pragma unroll
    for (int c = 0; c < 5; ++c) sc[t * 5 + c] = lg[c] * inv5;

    __shared__ float wmaxA[4], wsumA[4];
    float wm = as;
    #pragma unroll
    for (int off = 32; off > 0; off >>= 1) wm = fmaxf(wm, __shfl_xor(wm, off, 64));
    if (lane == 0) wmaxA[wave] = wm;
    __syncthreads();
    float mx = fmaxf(fmaxf(wmaxA[0], wmaxA[1]), fmaxf(wmaxA[2], wmaxA[3]));
    float e = __expf(as - mx);
    float wsum = e;
    #pragma unroll
    for (int off = 32; off > 0; off >>= 1) wsum += __shfl_xor(wsum, off, 64);
    if (lane == 0) wsumA[wave] = wsum;
    __syncthreads();
    float inv = 1.f / (wsumA[0] + wsumA[1] + wsumA[2] + wsumA[3]);
    probs_out[(size_t)bq * Kn + t] = e * inv;

    float4* so4 = (float4*)(scores_out + (size_t)bq * Kn * 5);
    const float4* sc4 = (const float4*)sc;
    so4[t] = sc4[t];
    if (t < 64) so4[256 + t] = sc4[256 + t];
}

__global__ __launch_bounds__(256) void pv_kernel(
    const float* __restrict__ probs, const float* __restrict__ m,
    float* __restrict__ out)
{
    int bid = blockIdx.x;
    int dt = bid % 6;
    int qt = (bid / 6) & 31;
    int b  = bid / 192;
    __shared__ float p[8][Kn];
    __shared__ float part[8][128];
    int t = threadIdx.x;
    int kh = t >> 7;
    int c  = t & 127;
    int d  = dt * 128 + c;

    const float* psrc = probs + ((size_t)(b * Qn + qt * 8) * Kn);
    #pragma unroll
    for (int i = 0; i < 8; ++i) p[i][t] = psrc[t + i * Kn];
    __syncthreads();

    float acc[8] = {0.f, 0.f, 0.f, 0.f, 0.f, 0.f, 0.f, 0.f};
    const float* mb = m + (size_t)b * Kn * Dn + d;
    int k0 = kh * 128;
    for (int kk = k0; kk < k0 + 128; kk += 4) {
        float mv0 = mb[(size_t)(kk + 0) * Dn];
        float mv1 = mb[(size_t)(kk + 1) * Dn];
        float mv2 = mb[(size_t)(kk + 2) * Dn];
        float mv3 = mb[(size_t)(kk + 3) * Dn];
        #pragma unroll
        for (int qi = 0; qi < 8; ++qi) {
            float4 pv = *(const float4*)&p[qi][kk];
            acc[qi] = fmaf(pv.x, mv0, acc[qi]);
            acc[qi] = fmaf(pv.y, mv1, acc[qi]);
            acc[qi] = fmaf(pv.z, mv2, acc[qi]);
            acc[qi] = fmaf(pv.w, mv3, acc[qi]);
        }
    }
    if (kh == 1) {
        #pragma unroll
        for (int qi = 0; qi < 8; ++qi) part[qi][c] = acc[qi];
    }
    __syncthreads();
    if (kh == 0) {
        float* ob = out + ((size_t)(b * Qn + qt * 8) * Dn) + d;
        #pragma unroll
        for (int qi = 0; qi < 8; ++qi) ob[qi * Dn] = acc[qi] + part[qi][c];
    }
}

extern "C" void kernel_launch(void* const* d_in, const int* in_sizes, int n_in,
                              void* d_out, int out_size, void* d_ws, size_t ws_size,
                              hipStream_t stream) {
    const float* q   = (const float*)d_in[0];
    const float* k   = (const float*)d_in[1];
    const float* m   = (const float*)d_in[2];
    const float* am  = (const float*)d_in[3];
    const float* emb = (const float*)d_in[4];
    const float* W1  = (const float*)d_in[5];
    const float* b1  = (const float*)d_in[6];
    const float* W2  = (const float*)d_in[7];
    const float* b2  = (const float*)d_in[8];
    const int*   lm  = (const int*)d_in[9];

    float* out         = (float*)d_out;
    float* out_content = out;                 // [4,256,768]
    float* out_scores  = out + Bn * Qn * Dn;  // [4,256,256,5]

    float* ws    = (float*)d_ws;
    float* probs = ws + WS_PROBS;

    void* kargs[] = {
        (void*)&q, (void*)&k, (void*)&m, (void*)&am, (void*)&emb,
        (void*)&W1, (void*)&b1, (void*)&W2, (void*)&b2, (void*)&lm,
        (void*)&out_scores, (void*)&out_content, (void*)&ws
    };
    hipError_t err = hipLaunchCooperativeKernel(
        (void*)mega_kernel, dim3(768), dim3(256), kargs, 0, stream);
    if (err != hipSuccess) {
        (void)hipGetLastError();  // clear sticky error, use fallback path
        proj_kernel<<<537, 256, 0, stream>>>(q, k, emb, W1, W2, ws);
        score_kernel<<<Bn * Qn, 256, 0, stream>>>(ws, am, lm, b1, b2, out_scores, probs);
        pv_kernel<<<Bn * (Qn / 8) * 6, 256, 0, stream>>>(probs, m, out_content);
    }
}

// Round 4
// 30.444 us; speedup vs baseline: 6.6380x; 6.6380x over previous
//
#include <hip/hip_runtime.h>

// Problem: B=4, Q=256, K=256, H=768, D=768, NUM_LEN=100
// s = q + k + emb[lm]  (never materialized; all linear maps distribute)
// ws float layout: qP[1024][8] @0, kP[1024][8] @8192, eP[100][8] @16384
#define Hn 768
#define Bn 4
#define Qn 256
#define Kn 256
#define Dn 768
#define WS_KP 8192
#define WS_EP 16384

__device__ __forceinline__ void fma4(float4& a, float s, const float4& v) {
    a.x = fmaf(s, v.x, a.x); a.y = fmaf(s, v.y, a.y);
    a.z = fmaf(s, v.z, a.z); a.w = fmaf(s, v.w, a.w);
}

// ---------------- kernel 1: projections (wave per row) ----------------------
__global__ __launch_bounds__(256) void proj_kernel(
    const float* __restrict__ q, const float* __restrict__ k,
    const float* __restrict__ emb, const float* __restrict__ W1,
    const float* __restrict__ W2, float* __restrict__ ws)
{
    int wid  = blockIdx.x * 4 + (threadIdx.x >> 6);
    int lane = threadIdx.x & 63;
    const float* src;
    float* dst;
    if (wid < 1024)      { src = q + wid * Hn;            dst = ws + wid * 8; }
    else if (wid < 2048) { src = k + (wid - 1024) * Hn;   dst = ws + WS_KP + (wid - 1024) * 8; }
    else {
        int r = wid - 2048;
        if (r >= 100) return;
        src = emb + r * Hn; dst = ws + WS_EP + r * 8;
    }
    float acc[6] = {0.f, 0.f, 0.f, 0.f, 0.f, 0.f};
    #pragma unroll
    for (int i = 0; i < 3; ++i) {                 // 3 x (64 lanes x float4)
        int h = i * 256 + lane * 4;
        float4 x  = *(const float4*)&src[h];
        float4 w1 = *(const float4*)&W1[h];
        acc[0] += x.x * w1.x + x.y * w1.y + x.z * w1.z + x.w * w1.w;
        #pragma unroll
        for (int c = 0; c < 5; ++c) {
            float4 w2 = *(const float4*)&W2[c * Hn + h];
            acc[1 + c] += x.x * w2.x + x.y * w2.y + x.z * w2.z + x.w * w2.w;
        }
    }
    #pragma unroll
    for (int j = 0; j < 6; ++j) {
        float v = acc[j];
        #pragma unroll
        for (int off = 32; off > 0; off >>= 1)
            v += __shfl_xor(v, off, 64);
        if (lane == 0) dst[j] = v;
    }
}

// ---------------- kernel 2: fused score + softmax + PV ----------------------
// block = (b:4, qt:32 [8 q rows], dt:6 [128 d cols]) = 768 blocks, 256 thr.
// Score phase: thread t = k index; kP row loaded once, reused for 8 q rows.
// probs kept in LDS, never touches global. scores written by dt==0 blocks.
// PV phase: kh = t>>5 (8 k-groups of 32), c4 = t&31 (float4 d col).
__global__ __launch_bounds__(256, 3) void fused_kernel(
    const float* __restrict__ ws_proj, const float* __restrict__ m,
    const float* __restrict__ am, const int* __restrict__ lm,
    const float* __restrict__ b1, const float* __restrict__ b2,
    float* __restrict__ scores_out, float* __restrict__ content_out)
{
    __shared__ float p[8][Kn];            // 8 KB probs
    __shared__ float4 parts[8][8][32];    // 32 KB pv partials
    __shared__ float sc[Kn * 5];          // 5 KB scores staging
    __shared__ float wmaxA[4], wsumA[4];

    int bid = blockIdx.x;
    int dt = bid % 6;
    int qt = (bid / 6) & 31;
    int b  = bid / 192;
    int q0 = qt * 8;
    int t = threadIdx.x;
    int wave = t >> 6, lane = t & 63;

    const float* qP = ws_proj;
    const float* kP = ws_proj + WS_KP;
    const float* eP = ws_proj + WS_EP;

    // k-row projection: same for all 8 q rows of this block
    int krow = b * Kn + t;
    float4 ka = *(const float4*)&kP[krow * 8];
    float4 kb = *(const float4*)&kP[krow * 8 + 4];
    float kp[6] = {ka.x, ka.y, ka.z, ka.w, kb.x, kb.y};
    float b1v = b1[0];
    float b2v[5] = {b2[0], b2[1], b2[2], b2[3], b2[4]};

    for (int qi = 0; qi < 8; ++qi) {
        int bq = b * Qn + q0 + qi;
        float qp[6];
        #pragma unroll
        for (int j = 0; j < 6; ++j) qp[j] = qP[bq * 8 + j];   // uniform

        int l = lm[(size_t)bq * Kn + t];
        float4 ea = *(const float4*)&eP[l * 8];
        float4 eb = *(const float4*)&eP[l * 8 + 4];
        float ep[6] = {ea.x, ea.y, ea.z, ea.w, eb.x, eb.y};

        float amv = am[(size_t)bq * Kn + t];
        float as  = (qp[0] + kp[0] + ep[0] + b1v) * amv;

        // softmax over K (wave shfl + tiny LDS combine)
        float wm = as;
        #pragma unroll
        for (int off = 32; off > 0; off >>= 1) wm = fmaxf(wm, __shfl_xor(wm, off, 64));
        if (lane == 0) wmaxA[wave] = wm;
        __syncthreads();
        float mx = fmaxf(fmaxf(wmaxA[0], wmaxA[1]), fmaxf(wmaxA[2], wmaxA[3]));
        float e = __expf(as - mx);
        float wsum = e;
        #pragma unroll
        for (int off = 32; off > 0; off >>= 1) wsum += __shfl_xor(wsum, off, 64);
        if (lane == 0) wsumA[wave] = wsum;
        __syncthreads();
        float inv = 1.f / (wsumA[0] + wsumA[1] + wsumA[2] + wsumA[3]);
        p[qi][t] = e * inv;

        // 5-class softmax -> scores (only dt==0 blocks write)
        if (dt == 0) {
            float lg[5];
            float mx5 = -1e30f;
            #pragma unroll
            for (int c = 0; c < 5; ++c) {
                lg[c] = qp[c + 1] + kp[c + 1] + ep[c + 1] + b2v[c];
                mx5 = fmaxf(mx5, lg[c]);
            }
            float s5 = 0.f;
            #pragma unroll
            for (int c = 0; c < 5; ++c) { lg[c] = __expf(lg[c] - mx5); s5 += lg[c]; }
            float inv5 = 1.f / s5;
            #pragma unroll
            for (int c = 0; c < 5; ++c) sc[t * 5 + c] = lg[c] * inv5;
            __syncthreads();
            float4* so4 = (float4*)(scores_out + (size_t)bq * Kn * 5);
            const float4* sc4 = (const float4*)sc;
            so4[t] = sc4[t];
            if (t < 64) so4[256 + t] = sc4[256 + t];
        }
        __syncthreads();
    }

    // -------- PV: content[b, q0..q0+7, dt*128..+127] = p @ m ---------------
    int kh = t >> 5;
    int c4 = t & 31;
    float4 acc[8];
    #pragma unroll
    for (int qi = 0; qi < 8; ++qi) acc[qi] = make_float4(0.f, 0.f, 0.f, 0.f);

    #pragma unroll
    for (int g = 0; g < 8; ++g) {
        int k0 = (kh << 5) + (g << 2);
        const float* mb = m + (size_t)(b * Kn + k0) * Dn + dt * 128 + (c4 << 2);
        float4 m0 = *(const float4*)(mb);
        float4 m1 = *(const float4*)(mb + Dn);
        float4 m2 = *(const float4*)(mb + 2 * Dn);
        float4 m3 = *(const float4*)(mb + 3 * Dn);
        #pragma unroll
        for (int qi = 0; qi < 8; ++qi) {
            float4 pv = *(const float4*)&p[qi][k0];   // broadcast read
            fma4(acc[qi], pv.x, m0);
            fma4(acc[qi], pv.y, m1);
            fma4(acc[qi], pv.z, m2);
            fma4(acc[qi], pv.w, m3);
        }
    }
    #pragma unroll
    for (int qi = 0; qi < 8; ++qi) parts[kh][qi][c4] = acc[qi];
    __syncthreads();

    int qi2 = t >> 5, c42 = t & 31;
    float4 s = parts[0][qi2][c42];
    #pragma unroll
    for (int kk = 1; kk < 8; ++kk) {
        float4 v = parts[kk][qi2][c42];
        s.x += v.x; s.y += v.y; s.z += v.z; s.w += v.w;
    }
    *(float4*)(content_out + (size_t)(b * Qn + q0 + qi2) * Dn + dt * 128 + (c42 << 2)) = s;
}

extern "C" void kernel_launch(void* const* d_in, const int* in_sizes, int n_in,
                              void* d_out, int out_size, void* d_ws, size_t ws_size,
                              hipStream_t stream) {
    const float* q   = (const float*)d_in[0];
    const float* k   = (const float*)d_in[1];
    const float* m   = (const float*)d_in[2];
    const float* am  = (const float*)d_in[3];
    const float* emb = (const float*)d_in[4];
    const float* W1  = (const float*)d_in[5];
    const float* b1  = (const float*)d_in[6];
    const float* W2  = (const float*)d_in[7];
    const float* b2  = (const float*)d_in[8];
    const int*   lm  = (const int*)d_in[9];

    float* out         = (float*)d_out;
    float* out_content = out;                 // [4,256,768]
    float* out_scores  = out + Bn * Qn * Dn;  // [4,256,256,5]

    float* ws = (float*)d_ws;

    proj_kernel<<<537, 256, 0, stream>>>(q, k, emb, W1, W2, ws);
    fused_kernel<<<Bn * (Qn / 8) * 6, 256, 0, stream>>>(
        ws, m, am, lm, b1, b2, out_scores, out_content);
}

// Round 5
// 24.473 us; speedup vs baseline: 8.2573x; 1.2440x over previous
//
#include <hip/hip_runtime.h>

// Problem: B=4, Q=256, K=256, H=768, D=768, NUM_LEN=100
// s = q + k + emb[lm]  (never materialized; all linear maps distribute)
// ws float layout: qP[1024][8] @0, kP[1024][8] @8192, eP[100][8] @16384
#define Hn 768
#define Bn 4
#define Qn 256
#define Kn 256
#define Dn 768
#define WS_KP 8192
#define WS_EP 16384

__device__ __forceinline__ void fma4(float4& a, float s, const float4& v) {
    a.x = fmaf(s, v.x, a.x); a.y = fmaf(s, v.y, a.y);
    a.z = fmaf(s, v.z, a.z); a.w = fmaf(s, v.w, a.w);
}

// ---------------- kernel 1: projections (wave per row) ----------------------
__global__ __launch_bounds__(256) void proj_kernel(
    const float* __restrict__ q, const float* __restrict__ k,
    const float* __restrict__ emb, const float* __restrict__ W1,
    const float* __restrict__ W2, float* __restrict__ ws)
{
    int wid  = blockIdx.x * 4 + (threadIdx.x >> 6);
    int lane = threadIdx.x & 63;
    const float* src;
    float* dst;
    if (wid < 1024)      { src = q + wid * Hn;            dst = ws + wid * 8; }
    else if (wid < 2048) { src = k + (wid - 1024) * Hn;   dst = ws + WS_KP + (wid - 1024) * 8; }
    else {
        int r = wid - 2048;
        if (r >= 100) return;
        src = emb + r * Hn; dst = ws + WS_EP + r * 8;
    }
    float acc[6] = {0.f, 0.f, 0.f, 0.f, 0.f, 0.f};
    #pragma unroll
    for (int i = 0; i < 3; ++i) {
        int h = i * 256 + lane * 4;
        float4 x  = *(const float4*)&src[h];
        float4 w1 = *(const float4*)&W1[h];
        acc[0] += x.x * w1.x + x.y * w1.y + x.z * w1.z + x.w * w1.w;
        #pragma unroll
        for (int c = 0; c < 5; ++c) {
            float4 w2 = *(const float4*)&W2[c * Hn + h];
            acc[1 + c] += x.x * w2.x + x.y * w2.y + x.z * w2.z + x.w * w2.w;
        }
    }
    #pragma unroll
    for (int j = 0; j < 6; ++j) {
        float v = acc[j];
        #pragma unroll
        for (int off = 32; off > 0; off >>= 1)
            v += __shfl_xor(v, off, 64);
        if (lane == 0) dst[j] = v;
    }
}

// ---------------- kernel 2: fused score + softmax + PV ----------------------
// block = (b:4, qt:32 [8 q rows], dt:6 [128 d cols]) = 768 blocks, 256 thr.
// Score phase: WAVE per q-row (2 rows/wave), all-shfl softmax, NO barriers.
// probs kept in LDS. scores written directly by dt==0 blocks (L2 merges).
// PV phase: kh = t>>5 (8 k-groups of 32), c4 = t&31 (float4 d col).
__global__ __launch_bounds__(256, 4) void fused_kernel(
    const float* __restrict__ ws_proj, const float* __restrict__ m,
    const float* __restrict__ am, const int* __restrict__ lm,
    const float* __restrict__ b1, const float* __restrict__ b2,
    float* __restrict__ scores_out, float* __restrict__ content_out)
{
    __shared__ float p[8][Kn];            // 8 KB probs
    __shared__ float4 parts[8][8][32];    // 32 KB pv partials

    int bid = blockIdx.x;
    int dt = bid % 6;
    int qt = (bid / 6) & 31;
    int b  = bid / 192;
    int q0 = qt * 8;
    int t = threadIdx.x;
    int wave = t >> 6, lane = t & 63;

    const float* qP = ws_proj;
    const float* kP = ws_proj + WS_KP;
    const float* eP = ws_proj + WS_EP;

    float b1v = b1[0];
    float b2v[5] = {b2[0], b2[1], b2[2], b2[3], b2[4]};

    // k projections: lane owns k = j*64+lane, j=0..3 (shared by both rows)
    float kp[4][6];
    #pragma unroll
    for (int j = 0; j < 4; ++j) {
        const float* kr = &kP[(b * Kn + j * 64 + lane) * 8];
        float4 a  = *(const float4*)kr;
        float4 bb = *(const float4*)(kr + 4);
        kp[j][0] = a.x; kp[j][1] = a.y; kp[j][2] = a.z;
        kp[j][3] = a.w; kp[j][4] = bb.x; kp[j][5] = bb.y;
    }

    #pragma unroll
    for (int rr = 0; rr < 2; ++rr) {
        int qi = wave + rr * 4;                  // this wave's q-row
        int bq = b * Qn + q0 + qi;
        float qp[6];
        #pragma unroll
        for (int j2 = 0; j2 < 6; ++j2) qp[j2] = qP[bq * 8 + j2];  // uniform

        int   l[4];
        float as[4];
        #pragma unroll
        for (int j = 0; j < 4; ++j) {
            int kk = j * 64 + lane;
            l[j] = lm[(size_t)bq * Kn + kk];
            float e0  = eP[l[j] * 8];
            float amv = am[(size_t)bq * Kn + kk];
            as[j] = (qp[0] + kp[j][0] + e0 + b1v) * amv;
        }
        // in-wave softmax over 256 k
        float mx = fmaxf(fmaxf(as[0], as[1]), fmaxf(as[2], as[3]));
        #pragma unroll
        for (int off = 32; off > 0; off >>= 1)
            mx = fmaxf(mx, __shfl_xor(mx, off, 64));
        float e[4], sum = 0.f;
        #pragma unroll
        for (int j = 0; j < 4; ++j) { e[j] = __expf(as[j] - mx); sum += e[j]; }
        #pragma unroll
        for (int off = 32; off > 0; off >>= 1)
            sum += __shfl_xor(sum, off, 64);
        float inv = 1.f / sum;
        #pragma unroll
        for (int j = 0; j < 4; ++j) p[qi][j * 64 + lane] = e[j] * inv;

        // 5-class softmax -> direct store (dt==0 blocks only)
        if (dt == 0) {
            #pragma unroll
            for (int j = 0; j < 4; ++j) {
                const float* er = &eP[l[j] * 8];
                float4 ea = *(const float4*)er;
                float4 eb = *(const float4*)(er + 4);
                float epc[5] = {ea.y, ea.z, ea.w, eb.x, eb.y};
                float lg[5];
                float mx5 = -1e30f;
                #pragma unroll
                for (int c = 0; c < 5; ++c) {
                    lg[c] = qp[c + 1] + kp[j][c + 1] + epc[c] + b2v[c];
                    mx5 = fmaxf(mx5, lg[c]);
                }
                float s5 = 0.f;
                #pragma unroll
                for (int c = 0; c < 5; ++c) { lg[c] = __expf(lg[c] - mx5); s5 += lg[c]; }
                float inv5 = 1.f / s5;
                float* so = scores_out + ((size_t)bq * Kn + j * 64 + lane) * 5;
                #pragma unroll
                for (int c = 0; c < 5; ++c) so[c] = lg[c] * inv5;
            }
        }
    }
    __syncthreads();   // p complete

    // -------- PV: content[b, q0..q0+7, dt*128..+127] = p @ m ---------------
    int kh = t >> 5;
    int c4 = t & 31;
    float4 acc[8];
    #pragma unroll
    for (int qi = 0; qi < 8; ++qi) acc[qi] = make_float4(0.f, 0.f, 0.f, 0.f);

    #pragma unroll
    for (int g = 0; g < 8; ++g) {
        int k0 = (kh << 5) + (g << 2);
        const float* mb = m + (size_t)(b * Kn + k0) * Dn + dt * 128 + (c4 << 2);
        float4 m0 = *(const float4*)(mb);
        float4 m1 = *(const float4*)(mb + Dn);
        float4 m2 = *(const float4*)(mb + 2 * Dn);
        float4 m3 = *(const float4*)(mb + 3 * Dn);
        #pragma unroll
        for (int qi = 0; qi < 8; ++qi) {
            float4 pv = *(const float4*)&p[qi][k0];   // 2-addr broadcast read
            fma4(acc[qi], pv.x, m0);
            fma4(acc[qi], pv.y, m1);
            fma4(acc[qi], pv.z, m2);
            fma4(acc[qi], pv.w, m3);
        }
    }
    #pragma unroll
    for (int qi = 0; qi < 8; ++qi) parts[kh][qi][c4] = acc[qi];
    __syncthreads();

    int qi2 = t >> 5, c42 = t & 31;
    float4 s = parts[0][qi2][c42];
    #pragma unroll
    for (int kk = 1; kk < 8; ++kk) {
        float4 v = parts[kk][qi2][c42];
        s.x += v.x; s.y += v.y; s.z += v.z; s.w += v.w;
    }
    *(float4*)(content_out + (size_t)(b * Qn + q0 + qi2) * Dn + dt * 128 + (c42 << 2)) = s;
}

extern "C" void kernel_launch(void* const* d_in, const int* in_sizes, int n_in,
                              void* d_out, int out_size, void* d_ws, size_t ws_size,
                              hipStream_t stream) {
    const float* q   = (const float*)d_in[0];
    const float* k   = (const float*)d_in[1];
    const float* m   = (const float*)d_in[2];
    const float* am  = (const float*)d_in[3];
    const float* emb = (const float*)d_in[4];
    const float* W1  = (const float*)d_in[5];
    const float* b1  = (const float*)d_in[6];
    const float* W2  = (const float*)d_in[7];
    const float* b2  = (const float*)d_in[8];
    const int*   lm  = (const int*)d_in[9];

    float* out         = (float*)d_out;
    float* out_content = out;                 // [4,256,768]
    float* out_scores  = out + Bn * Qn * Dn;  // [4,256,256,5]

    float* ws = (float*)d_ws;

    proj_kernel<<<537, 256, 0, stream>>>(q, k, emb, W1, W2, ws);
    fused_kernel<<<Bn * (Qn / 8) * 6, 256, 0, stream>>>(
        ws, m, am, lm, b1, b2, out_scores, out_content);
}

// Round 6
// 24.036 us; speedup vs baseline: 8.4076x; 1.0182x over previous
//
#include <hip/hip_runtime.h>

// Problem: B=4, Q=256, K=256, H=768, D=768, NUM_LEN=100
// s = q + k + emb[lm]  (never materialized; all linear maps distribute)
// ws float layout: qP[1024][8] @0, kP[1024][8] @8192, eP[100][8] @16384
#define Hn 768
#define Bn 4
#define Qn 256
#define Kn 256
#define Dn 768
#define WS_KP 8192
#define WS_EP 16384

__device__ __forceinline__ void fma4(float4& a, float s, const float4& v) {
    a.x = fmaf(s, v.x, a.x); a.y = fmaf(s, v.y, a.y);
    a.z = fmaf(s, v.z, a.z); a.w = fmaf(s, v.w, a.w);
}

// ---------------- kernel 1: projections (wave per row) ----------------------
__global__ __launch_bounds__(256) void proj_kernel(
    const float* __restrict__ q, const float* __restrict__ k,
    const float* __restrict__ emb, const float* __restrict__ W1,
    const float* __restrict__ W2, float* __restrict__ ws)
{
    int wid  = blockIdx.x * 4 + (threadIdx.x >> 6);
    int lane = threadIdx.x & 63;
    const float* src;
    float* dst;
    if (wid < 1024)      { src = q + wid * Hn;            dst = ws + wid * 8; }
    else if (wid < 2048) { src = k + (wid - 1024) * Hn;   dst = ws + WS_KP + (wid - 1024) * 8; }
    else {
        int r = wid - 2048;
        if (r >= 100) return;
        src = emb + r * Hn; dst = ws + WS_EP + r * 8;
    }
    float acc[6] = {0.f, 0.f, 0.f, 0.f, 0.f, 0.f};
    #pragma unroll
    for (int i = 0; i < 3; ++i) {
        int h = i * 256 + lane * 4;
        float4 x  = *(const float4*)&src[h];
        float4 w1 = *(const float4*)&W1[h];
        acc[0] += x.x * w1.x + x.y * w1.y + x.z * w1.z + x.w * w1.w;
        #pragma unroll
        for (int c = 0; c < 5; ++c) {
            float4 w2 = *(const float4*)&W2[c * Hn + h];
            acc[1 + c] += x.x * w2.x + x.y * w2.y + x.z * w2.z + x.w * w2.w;
        }
    }
    #pragma unroll
    for (int j = 0; j < 6; ++j) {
        float v = acc[j];
        #pragma unroll
        for (int off = 32; off > 0; off >>= 1)
            v += __shfl_xor(v, off, 64);
        if (lane == 0) dst[j] = v;
    }
}

// ---------------- kernel 2: fused score + softmax + PV ----------------------
// block = (b:4, qt:32 [8 q rows], dt:6 [128 d cols]) = 768 blocks, 256 thr.
// Score phase: WAVE per q-row (2 rows/wave), all-shfl softmax, no barriers.
// 5-class scores: each dt-replica handles its own k-slice [dt*43, ...) so the
// work/stores are balanced across all 768 blocks (was: only dt==0).
// PV phase: kh = t>>5 (8 k-groups of 32), c4 = t&31 (float4 d col); first two
// m-tiles prefetched into regs before the score phase (L2 latency hiding).
__global__ __launch_bounds__(256, 4) void fused_kernel(
    const float* __restrict__ ws_proj, const float* __restrict__ m,
    const float* __restrict__ am, const int* __restrict__ lm,
    const float* __restrict__ b1, const float* __restrict__ b2,
    float* __restrict__ scores_out, float* __restrict__ content_out)
{
    __shared__ float p[8][Kn];            // 8 KB probs
    __shared__ float4 parts[8][8][32];    // 32 KB pv partials

    int bid = blockIdx.x;
    int dt = bid % 6;
    int qt = (bid / 6) & 31;
    int b  = bid / 192;
    int q0 = qt * 8;
    int t = threadIdx.x;
    int wave = t >> 6, lane = t & 63;

    const float* qP = ws_proj;
    const float* kP = ws_proj + WS_KP;
    const float* eP = ws_proj + WS_EP;

    // ---- PV prefetch: first two m-tiles (g=0,1) into registers ----
    int kh = t >> 5;
    int c4 = t & 31;
    const float* mb0 = m + (size_t)(b * Kn + (kh << 5)) * Dn + dt * 128 + (c4 << 2);
    float4 pm0 = *(const float4*)(mb0);
    float4 pm1 = *(const float4*)(mb0 + Dn);
    float4 pm2 = *(const float4*)(mb0 + 2 * Dn);
    float4 pm3 = *(const float4*)(mb0 + 3 * Dn);
    float4 pm4 = *(const float4*)(mb0 + 4 * Dn);
    float4 pm5 = *(const float4*)(mb0 + 5 * Dn);
    float4 pm6 = *(const float4*)(mb0 + 6 * Dn);
    float4 pm7 = *(const float4*)(mb0 + 7 * Dn);

    float b1v = b1[0];
    float b2v[5] = {b2[0], b2[1], b2[2], b2[3], b2[4]};

    // this block's k-slice for the 5-class scores output
    int slo = dt * 43;
    int shi = (dt == 5) ? 256 : slo + 43;

    // k projections: lane owns k = j*64+lane, j=0..3 (shared by both rows)
    float kp[4][6];
    #pragma unroll
    for (int j = 0; j < 4; ++j) {
        const float* kr = &kP[(b * Kn + j * 64 + lane) * 8];
        float4 a  = *(const float4*)kr;
        float4 bb = *(const float4*)(kr + 4);
        kp[j][0] = a.x; kp[j][1] = a.y; kp[j][2] = a.z;
        kp[j][3] = a.w; kp[j][4] = bb.x; kp[j][5] = bb.y;
    }

    #pragma unroll
    for (int rr = 0; rr < 2; ++rr) {
        int qi = wave + rr * 4;                  // this wave's q-row
        int bq = b * Qn + q0 + qi;
        float qp[6];
        #pragma unroll
        for (int j2 = 0; j2 < 6; ++j2) qp[j2] = qP[bq * 8 + j2];  // uniform

        int   l[4];
        float as[4];
        #pragma unroll
        for (int j = 0; j < 4; ++j) {
            int kk = j * 64 + lane;
            l[j] = lm[(size_t)bq * Kn + kk];
            float e0  = eP[l[j] * 8];
            float amv = am[(size_t)bq * Kn + kk];
            as[j] = (qp[0] + kp[j][0] + e0 + b1v) * amv;
        }
        // in-wave softmax over 256 k
        float mx = fmaxf(fmaxf(as[0], as[1]), fmaxf(as[2], as[3]));
        #pragma unroll
        for (int off = 32; off > 0; off >>= 1)
            mx = fmaxf(mx, __shfl_xor(mx, off, 64));
        float e[4], sum = 0.f;
        #pragma unroll
        for (int j = 0; j < 4; ++j) { e[j] = __expf(as[j] - mx); sum += e[j]; }
        #pragma unroll
        for (int off = 32; off > 0; off >>= 1)
            sum += __shfl_xor(sum, off, 64);
        float inv = 1.f / sum;
        #pragma unroll
        for (int j = 0; j < 4; ++j) p[qi][j * 64 + lane] = e[j] * inv;

        // 5-class softmax -> direct store, k-slice [slo,shi) only
        #pragma unroll
        for (int j = 0; j < 4; ++j) {
            int kk = j * 64 + lane;
            if (kk >= slo && kk < shi) {
                const float* er = &eP[l[j] * 8];
                float4 ea = *(const float4*)er;
                float4 eb = *(const float4*)(er + 4);
                float epc[5] = {ea.y, ea.z, ea.w, eb.x, eb.y};
                float lg[5];
                float mx5 = -1e30f;
                #pragma unroll
                for (int c = 0; c < 5; ++c) {
                    lg[c] = qp[c + 1] + kp[j][c + 1] + epc[c] + b2v[c];
                    mx5 = fmaxf(mx5, lg[c]);
                }
                float s5 = 0.f;
                #pragma unroll
                for (int c = 0; c < 5; ++c) { lg[c] = __expf(lg[c] - mx5); s5 += lg[c]; }
                float inv5 = 1.f / s5;
                float* so = scores_out + ((size_t)bq * Kn + kk) * 5;
                #pragma unroll
                for (int c = 0; c < 5; ++c) so[c] = lg[c] * inv5;
            }
        }
    }
    __syncthreads();   // p complete

    // -------- PV: content[b, q0..q0+7, dt*128..+127] = p @ m ---------------
    float4 acc[8];
    #pragma unroll
    for (int qi = 0; qi < 8; ++qi) acc[qi] = make_float4(0.f, 0.f, 0.f, 0.f);

    #pragma unroll
    for (int g = 0; g < 8; ++g) {
        int k0 = (kh << 5) + (g << 2);
        float4 m0, m1, m2, m3;
        if (g == 0)      { m0 = pm0; m1 = pm1; m2 = pm2; m3 = pm3; }
        else if (g == 1) { m0 = pm4; m1 = pm5; m2 = pm6; m3 = pm7; }
        else {
            const float* mb = m + (size_t)(b * Kn + k0) * Dn + dt * 128 + (c4 << 2);
            m0 = *(const float4*)(mb);
            m1 = *(const float4*)(mb + Dn);
            m2 = *(const float4*)(mb + 2 * Dn);
            m3 = *(const float4*)(mb + 3 * Dn);
        }
        #pragma unroll
        for (int qi = 0; qi < 8; ++qi) {
            float4 pv = *(const float4*)&p[qi][k0];   // 2-addr broadcast read
            fma4(acc[qi], pv.x, m0);
            fma4(acc[qi], pv.y, m1);
            fma4(acc[qi], pv.z, m2);
            fma4(acc[qi], pv.w, m3);
        }
    }
    #pragma unroll
    for (int qi = 0; qi < 8; ++qi) parts[kh][qi][c4] = acc[qi];
    __syncthreads();

    int qi2 = t >> 5, c42 = t & 31;
    float4 s = parts[0][qi2][c42];
    #pragma unroll
    for (int kk = 1; kk < 8; ++kk) {
        float4 v = parts[kk][qi2][c42];
        s.x += v.x; s.y += v.y; s.z += v.z; s.w += v.w;
    }
    *(float4*)(content_out + (size_t)(b * Qn + q0 + qi2) * Dn + dt * 128 + (c42 << 2)) = s;
}

extern "C" void kernel_launch(void* const* d_in, const int* in_sizes, int n_in,
                              void* d_out, int out_size, void* d_ws, size_t ws_size,
                              hipStream_t stream) {
    const float* q   = (const float*)d_in[0];
    const float* k   = (const float*)d_in[1];
    const float* m   = (const float*)d_in[2];
    const float* am  = (const float*)d_in[3];
    const float* emb = (const float*)d_in[4];
    const float* W1  = (const float*)d_in[5];
    const float* b1  = (const float*)d_in[6];
    const float* W2  = (const float*)d_in[7];
    const float* b2  = (const float*)d_in[8];
    const int*   lm  = (const int*)d_in[9];

    float* out         = (float*)d_out;
    float* out_content = out;                 // [4,256,768]
    float* out_scores  = out + Bn * Qn * Dn;  // [4,256,256,5]

    float* ws = (float*)d_ws;

    proj_kernel<<<537, 256, 0, stream>>>(q, k, emb, W1, W2, ws);
    fused_kernel<<<Bn * (Qn / 8) * 6, 256, 0, stream>>>(
        ws, m, am, lm, b1, b2, out_scores, out_content);
}

// Round 7
// 22.775 us; speedup vs baseline: 8.8732x; 1.0554x over previous
//
#include <hip/hip_runtime.h>

// Problem: B=4, Q=256, K=256, H=768, D=768, NUM_LEN=100
// s = q + k + emb[lm]  (never materialized; all linear maps distribute)
// ws float layout: qP[1024][8] @0, kP[1024][8] @8192, eP[100][8] @16384
#define Hn 768
#define Bn 4
#define Qn 256
#define Kn 256
#define Dn 768
#define WS_KP 8192
#define WS_EP 16384

typedef float f32x2 __attribute__((ext_vector_type(2)));

// packed f32 fma with broadcast of one half of p to both halves (op_sel).
// acc.lo += p.lo * m.lo ; acc.hi += p.lo * m.hi
__device__ __forceinline__ void pkfma_lo(f32x2& acc, f32x2 p, f32x2 mm) {
    asm("v_pk_fma_f32 %0, %1, %2, %0 op_sel:[0,0,0] op_sel_hi:[0,1,1]"
        : "+v"(acc) : "v"(p), "v"(mm));
}
// acc.lo += p.hi * m.lo ; acc.hi += p.hi * m.hi
__device__ __forceinline__ void pkfma_hi(f32x2& acc, f32x2 p, f32x2 mm) {
    asm("v_pk_fma_f32 %0, %1, %2, %0 op_sel:[1,0,0] op_sel_hi:[1,1,1]"
        : "+v"(acc) : "v"(p), "v"(mm));
}

// ---------------- kernel 1: projections (wave per row) ----------------------
__global__ __launch_bounds__(256) void proj_kernel(
    const float* __restrict__ q, const float* __restrict__ k,
    const float* __restrict__ emb, const float* __restrict__ W1,
    const float* __restrict__ W2, float* __restrict__ ws)
{
    int wid  = blockIdx.x * 4 + (threadIdx.x >> 6);
    int lane = threadIdx.x & 63;
    const float* src;
    float* dst;
    if (wid < 1024)      { src = q + wid * Hn;            dst = ws + wid * 8; }
    else if (wid < 2048) { src = k + (wid - 1024) * Hn;   dst = ws + WS_KP + (wid - 1024) * 8; }
    else {
        int r = wid - 2048;
        if (r >= 100) return;
        src = emb + r * Hn; dst = ws + WS_EP + r * 8;
    }
    float acc[6] = {0.f, 0.f, 0.f, 0.f, 0.f, 0.f};
    #pragma unroll
    for (int i = 0; i < 3; ++i) {
        int h = i * 256 + lane * 4;
        float4 x  = *(const float4*)&src[h];
        float4 w1 = *(const float4*)&W1[h];
        acc[0] += x.x * w1.x + x.y * w1.y + x.z * w1.z + x.w * w1.w;
        #pragma unroll
        for (int c = 0; c < 5; ++c) {
            float4 w2 = *(const float4*)&W2[c * Hn + h];
            acc[1 + c] += x.x * w2.x + x.y * w2.y + x.z * w2.z + x.w * w2.w;
        }
    }
    #pragma unroll
    for (int j = 0; j < 6; ++j) {
        float v = acc[j];
        #pragma unroll
        for (int off = 32; off > 0; off >>= 1)
            v += __shfl_xor(v, off, 64);
        if (lane == 0) dst[j] = v;
    }
}

// ---------------- kernel 2: fused score + softmax + PV ----------------------
// block = (b:4, qt:32 [8 q rows], dt:6 [128 d cols]) = 768 blocks, 256 thr.
// Score phase: WAVE per q-row (2 rows/wave), all-shfl softmax, no barriers.
// 5-class scores balanced across dt-replicas (k-slice [dt*43, ...)).
// PV phase: kh = t>>5 (8 k-groups of 32), c4 = t&31 (float4 d col); first two
// m-tiles prefetched into regs; inner product via v_pk_fma_f32 (2 FMA/inst).
__global__ __launch_bounds__(256, 4) void fused_kernel(
    const float* __restrict__ ws_proj, const float* __restrict__ m,
    const float* __restrict__ am, const int* __restrict__ lm,
    const float* __restrict__ b1, const float* __restrict__ b2,
    float* __restrict__ scores_out, float* __restrict__ content_out)
{
    __shared__ float p[8][Kn];            // 8 KB probs
    __shared__ float4 parts[8][8][32];    // 32 KB pv partials

    int bid = blockIdx.x;
    int dt = bid % 6;
    int qt = (bid / 6) & 31;
    int b  = bid / 192;
    int q0 = qt * 8;
    int t = threadIdx.x;
    int wave = t >> 6, lane = t & 63;

    const float* qP = ws_proj;
    const float* kP = ws_proj + WS_KP;
    const float* eP = ws_proj + WS_EP;

    // ---- PV prefetch: first two m-tiles (g=0,1) into registers ----
    int kh = t >> 5;
    int c4 = t & 31;
    const float* mb0 = m + (size_t)(b * Kn + (kh << 5)) * Dn + dt * 128 + (c4 << 2);
    float4 pm0 = *(const float4*)(mb0);
    float4 pm1 = *(const float4*)(mb0 + Dn);
    float4 pm2 = *(const float4*)(mb0 + 2 * Dn);
    float4 pm3 = *(const float4*)(mb0 + 3 * Dn);
    float4 pm4 = *(const float4*)(mb0 + 4 * Dn);
    float4 pm5 = *(const float4*)(mb0 + 5 * Dn);
    float4 pm6 = *(const float4*)(mb0 + 6 * Dn);
    float4 pm7 = *(const float4*)(mb0 + 7 * Dn);

    float b1v = b1[0];
    float b2v[5] = {b2[0], b2[1], b2[2], b2[3], b2[4]};

    // this block's k-slice for the 5-class scores output
    int slo = dt * 43;
    int shi = (dt == 5) ? 256 : slo + 43;

    // k projections: lane owns k = j*64+lane, j=0..3 (shared by both rows)
    float kp[4][6];
    #pragma unroll
    for (int j = 0; j < 4; ++j) {
        const float* kr = &kP[(b * Kn + j * 64 + lane) * 8];
        float4 a  = *(const float4*)kr;
        float4 bb = *(const float4*)(kr + 4);
        kp[j][0] = a.x; kp[j][1] = a.y; kp[j][2] = a.z;
        kp[j][3] = a.w; kp[j][4] = bb.x; kp[j][5] = bb.y;
    }

    #pragma unroll
    for (int rr = 0; rr < 2; ++rr) {
        int qi = wave + rr * 4;                  // this wave's q-row
        int bq = b * Qn + q0 + qi;
        float qp[6];
        #pragma unroll
        for (int j2 = 0; j2 < 6; ++j2) qp[j2] = qP[bq * 8 + j2];  // uniform

        int   l[4];
        float as[4];
        #pragma unroll
        for (int j = 0; j < 4; ++j) {
            int kk = j * 64 + lane;
            l[j] = lm[(size_t)bq * Kn + kk];
            float e0  = eP[l[j] * 8];
            float amv = am[(size_t)bq * Kn + kk];
            as[j] = (qp[0] + kp[j][0] + e0 + b1v) * amv;
        }
        // in-wave softmax over 256 k
        float mx = fmaxf(fmaxf(as[0], as[1]), fmaxf(as[2], as[3]));
        #pragma unroll
        for (int off = 32; off > 0; off >>= 1)
            mx = fmaxf(mx, __shfl_xor(mx, off, 64));
        float e[4], sum = 0.f;
        #pragma unroll
        for (int j = 0; j < 4; ++j) { e[j] = __expf(as[j] - mx); sum += e[j]; }
        #pragma unroll
        for (int off = 32; off > 0; off >>= 1)
            sum += __shfl_xor(sum, off, 64);
        float inv = 1.f / sum;
        #pragma unroll
        for (int j = 0; j < 4; ++j) p[qi][j * 64 + lane] = e[j] * inv;

        // 5-class softmax -> direct store, k-slice [slo,shi) only
        #pragma unroll
        for (int j = 0; j < 4; ++j) {
            int kk = j * 64 + lane;
            if (kk >= slo && kk < shi) {
                const float* er = &eP[l[j] * 8];
                float4 ea = *(const float4*)er;
                float4 eb = *(const float4*)(er + 4);
                float epc[5] = {ea.y, ea.z, ea.w, eb.x, eb.y};
                float lg[5];
                float mx5 = -1e30f;
                #pragma unroll
                for (int c = 0; c < 5; ++c) {
                    lg[c] = qp[c + 1] + kp[j][c + 1] + epc[c] + b2v[c];
                    mx5 = fmaxf(mx5, lg[c]);
                }
                float s5 = 0.f;
                #pragma unroll
                for (int c = 0; c < 5; ++c) { lg[c] = __expf(lg[c] - mx5); s5 += lg[c]; }
                float inv5 = 1.f / s5;
                float* so = scores_out + ((size_t)bq * Kn + kk) * 5;
                #pragma unroll
                for (int c = 0; c < 5; ++c) so[c] = lg[c] * inv5;
            }
        }
    }
    __syncthreads();   // p complete

    // -------- PV: content[b, q0..q0+7, dt*128..+127] = p @ m ---------------
    f32x2 accA[8], accB[8];
    #pragma unroll
    for (int qi = 0; qi < 8; ++qi) {
        accA[qi] = (f32x2){0.f, 0.f};
        accB[qi] = (f32x2){0.f, 0.f};
    }

    #pragma unroll
    for (int g = 0; g < 8; ++g) {
        int k0 = (kh << 5) + (g << 2);
        float4 m0, m1, m2, m3;
        if (g == 0)      { m0 = pm0; m1 = pm1; m2 = pm2; m3 = pm3; }
        else if (g == 1) { m0 = pm4; m1 = pm5; m2 = pm6; m3 = pm7; }
        else {
            const float* mb = m + (size_t)(b * Kn + k0) * Dn + dt * 128 + (c4 << 2);
            m0 = *(const float4*)(mb);
            m1 = *(const float4*)(mb + Dn);
            m2 = *(const float4*)(mb + 2 * Dn);
            m3 = *(const float4*)(mb + 3 * Dn);
        }
        f32x2 m0A = {m0.x, m0.y}, m0B = {m0.z, m0.w};
        f32x2 m1A = {m1.x, m1.y}, m1B = {m1.z, m1.w};
        f32x2 m2A = {m2.x, m2.y}, m2B = {m2.z, m2.w};
        f32x2 m3A = {m3.x, m3.y}, m3B = {m3.z, m3.w};
        #pragma unroll
        for (int qi = 0; qi < 8; ++qi) {
            float4 pv = *(const float4*)&p[qi][k0];   // 2-addr broadcast read
            f32x2 p01 = {pv.x, pv.y};
            f32x2 p23 = {pv.z, pv.w};
            pkfma_lo(accA[qi], p01, m0A); pkfma_lo(accB[qi], p01, m0B);
            pkfma_hi(accA[qi], p01, m1A); pkfma_hi(accB[qi], p01, m1B);
            pkfma_lo(accA[qi], p23, m2A); pkfma_lo(accB[qi], p23, m2B);
            pkfma_hi(accA[qi], p23, m3A); pkfma_hi(accB[qi], p23, m3B);
        }
    }
    #pragma unroll
    for (int qi = 0; qi < 8; ++qi) {
        float4 v;
        v.x = accA[qi][0]; v.y = accA[qi][1];
        v.z = accB[qi][0]; v.w = accB[qi][1];
        parts[kh][qi][c4] = v;
    }
    __syncthreads();

    int qi2 = t >> 5, c42 = t & 31;
    float4 s = parts[0][qi2][c42];
    #pragma unroll
    for (int kk = 1; kk < 8; ++kk) {
        float4 v = parts[kk][qi2][c42];
        s.x += v.x; s.y += v.y; s.z += v.z; s.w += v.w;
    }
    *(float4*)(content_out + (size_t)(b * Qn + q0 + qi2) * Dn + dt * 128 + (c42 << 2)) = s;
}

extern "C" void kernel_launch(void* const* d_in, const int* in_sizes, int n_in,
                              void* d_out, int out_size, void* d_ws, size_t ws_size,
                              hipStream_t stream) {
    const float* q   = (const float*)d_in[0];
    const float* k   = (const float*)d_in[1];
    const float* m   = (const float*)d_in[2];
    const float* am  = (const float*)d_in[3];
    const float* emb = (const float*)d_in[4];
    const float* W1  = (const float*)d_in[5];
    const float* b1  = (const float*)d_in[6];
    const float* W2  = (const float*)d_in[7];
    const float* b2  = (const float*)d_in[8];
    const int*   lm  = (const int*)d_in[9];

    float* out         = (float*)d_out;
    float* out_content = out;                 // [4,256,768]
    float* out_scores  = out + Bn * Qn * Dn;  // [4,256,256,5]

    float* ws = (float*)d_ws;

    proj_kernel<<<537, 256, 0, stream>>>(q, k, emb, W1, W2, ws);
    fused_kernel<<<Bn * (Qn / 8) * 6, 256, 0, stream>>>(
        ws, m, am, lm, b1, b2, out_scores, out_content);
}